// Round 7
// baseline (96.811 us; speedup 1.0000x reference)
//
#include <hip/hip_runtime.h>

// Problem constants (compile-time)
constexpr int   H  = 376, W = 1241, B = 128;
constexpr int   HW = H * W;                 // 466616 (even)
constexpr int   NPAIR = HW / 2;             // 233308 pixel-pairs per batch
constexpr float FXc = 718.856f, FYc = 718.856f;
constexpr float CXc = 607.1928f, CYc = 185.2157f;

// Native clang vector types (required by __builtin_nontemporal_store)
typedef float  vfloat4 __attribute__((ext_vector_type(4)));
typedef float  vfloat2 __attribute__((ext_vector_type(2)));

// ---------------------------------------------------------------------------
// Kernel 1: per-batch rotation precompute.
// Builds M = R^T (so q = M @ p) and c = R^T @ t, stored as 3x float4 per batch:
//   row_i = (M[i][0], M[i][1], M[i][2], c_i)
// ---------------------------------------------------------------------------
__global__ void flow_rot_kernel(const float* __restrict__ rot,
                                const float* __restrict__ trans,
                                float* __restrict__ Mws) {
    int b = threadIdx.x;
    if (b >= B) return;
    float rx = rot[b * 3 + 0], ry = rot[b * 3 + 1], rz = rot[b * 3 + 2];
    float cx = cosf(rx), sx = sinf(rx);
    float cy = cosf(ry), sy = sinf(ry);
    float cz = cosf(rz), sz = sinf(rz);
    // R = Rz @ Ry @ Rx ; M = R^T
    float m00 = cz * cy,                m01 = sz * cy,                m02 = -sy;
    float m10 = cz * sy * sx - sz * cx, m11 = sz * sy * sx + cz * cx, m12 = cy * sx;
    float m20 = cz * sy * cx + sz * sx, m21 = sz * sy * cx - cz * sx, m22 = cy * cx;
    float t0 = trans[0], t1 = trans[1], t2 = trans[2];
    float4* o = reinterpret_cast<float4*>(Mws) + b * 3;
    o[0] = make_float4(m00, m01, m02, m00 * t0 + m01 * t1 + m02 * t2);
    o[1] = make_float4(m10, m11, m12, m10 * t0 + m11 * t1 + m12 * t2);
    o[2] = make_float4(m20, m21, m22, m20 * t0 + m21 * t1 + m22 * t2);
}

// ---------------------------------------------------------------------------
// Compute one pixel-pair -> vfloat4 (given its preloaded depth pair).
// ---------------------------------------------------------------------------
__device__ __forceinline__ vfloat4 pair_flow(int u, vfloat2 d2,
                                             const float4 r0, const float4 r1,
                                             const float4 r2) {
    const int n0 = u * 2;
    int y0 = n0 / W;            // constant divisor -> magic-mul
    int x0 = n0 - y0 * W;
    int x1 = x0 + 1, y1 = y0;
    if (x1 == W) { x1 = 0; y1 += 1; }   // row wrap (HW even -> never crosses batch)

    float xs[2] = { (float)x0, (float)x1 };
    float ys[2] = { (float)y0, (float)y1 };
    float ds[2] = { d2.x, d2.y };
    float fo[4];

#pragma unroll
    for (int i = 0; i < 2; ++i) {
        float px = (xs[i] - CXc) * (1.0f / FXc);
        float py = (ys[i] - CYc) * (1.0f / FYc);
        // s = M @ (px, py, 1)
        float s0 = fmaf(r0.x, px, fmaf(r0.y, py, r0.z));
        float s1 = fmaf(r1.x, px, fmaf(r1.y, py, r1.z));
        float s2 = fmaf(r2.x, px, fmaf(r2.y, py, r2.z));
        // q = d * s - c   (== R^T (d*n - t))
        float d  = ds[i];
        float q0 = fmaf(d, s0, -r0.w);
        float q1 = fmaf(d, s1, -r1.w);
        float q2 = fmaf(d, s2, -r2.w);
        float inv = __builtin_amdgcn_rcpf(q2);   // 1-ulp approx, threshold 7.9e-3
        fo[2 * i + 0] = fmaf(q0 * inv, FXc, CXc - xs[i]) * (1.0f / (float)W);
        fo[2 * i + 1] = fmaf(q1 * inv, FYc, CYc - ys[i]) * (1.0f / (float)H);
    }
    vfloat4 o;
    o.x = fo[0]; o.y = fo[1]; o.z = fo[2]; o.w = fo[3];
    return o;
}

// ---------------------------------------------------------------------------
// Kernel 2: main flow kernel. 2 pairs/thread, HAZARD-FREE ordering:
//   issue BOTH depth loads -> single vmcnt wait -> compute -> issue BOTH
//   NT stores (no subsequent wait touches vmcnt, so stores never stall us).
// R3 (95.5us) interleaved store0 before load1's wait, draining the store;
// this variant tests whether that ordering was the whole regression.
// Pair u1 = u0+256 keeps each load (512B) / store (1KB) burst contiguous
// per wave. b = blockIdx.y wave-uniform -> scalar M loads.
// ---------------------------------------------------------------------------
__global__ __launch_bounds__(256) void flow_main_kernel(
        const float* __restrict__ depth,
        const float* __restrict__ Mws,
        float* __restrict__ out) {
    const int b  = blockIdx.y;
    const int u0 = blockIdx.x * 512 + threadIdx.x;
    const int u1 = u0 + 256;
    const bool v0 = (u0 < NPAIR);
    const bool v1 = (u1 < NPAIR);

    // ---- both loads first ----
    vfloat2 dA, dB;
    if (v0) dA = *reinterpret_cast<const vfloat2*>(depth + 2 * u0);
    if (v1) dB = *reinterpret_cast<const vfloat2*>(depth + 2 * u1);

    const float4* Mb = reinterpret_cast<const float4*>(Mws) + b * 3;
    const float4 r0 = Mb[0];
    const float4 r1 = Mb[1];
    const float4 r2 = Mb[2];

    float* __restrict__ outb = out + (size_t)b * HW * 2;

    // ---- compute + stores last ----
    if (v0) {
        vfloat4 o = pair_flow(u0, dA, r0, r1, r2);
        __builtin_nontemporal_store(o, reinterpret_cast<vfloat4*>(outb + 4 * (size_t)u0));
    }
    if (v1) {
        vfloat4 o = pair_flow(u1, dB, r0, r1, r2);
        __builtin_nontemporal_store(o, reinterpret_cast<vfloat4*>(outb + 4 * (size_t)u1));
    }
}

// ---------------------------------------------------------------------------
extern "C" void kernel_launch(void* const* d_in, const int* in_sizes, int n_in,
                              void* d_out, int out_size, void* d_ws, size_t ws_size,
                              hipStream_t stream) {
    const float* rotations   = (const float*)d_in[0];   // (B, 3)
    const float* depth       = (const float*)d_in[1];   // (H, W)
    const float* translation = (const float*)d_in[2];   // (3,)
    float*       out         = (float*)d_out;           // (B, H, W, 2)
    float*       Mws         = (float*)d_ws;            // B * 12 floats = 6 KB

    flow_rot_kernel<<<1, 128, 0, stream>>>(rotations, translation, Mws);

    dim3 grid((NPAIR + 511) / 512, B);                  // (456, 128)
    flow_main_kernel<<<grid, 256, 0, stream>>>(depth, Mws, out);
}

// Round 8
// 85.359 us; speedup vs baseline: 1.1342x; 1.1342x over previous
//
#include <hip/hip_runtime.h>

// Problem constants (compile-time)
constexpr int   H  = 376, W = 1241, B = 128;
constexpr int   HW = H * W;                 // 466616 (even)
constexpr int   NPAIR = HW / 2;             // 233308 pixel-pairs per batch
constexpr float FXc = 718.856f, FYc = 718.856f;
constexpr float CXc = 607.1928f, CYc = 185.2157f;

// Native clang vector types (required by __builtin_nontemporal_store)
typedef float  vfloat4 __attribute__((ext_vector_type(4)));
typedef float  vfloat2 __attribute__((ext_vector_type(2)));

// ---------------------------------------------------------------------------
// Kernel 1: per-batch rotation precompute.
// Builds M = R^T (so q = M @ p) and c = R^T @ t, stored as 3x float4 per batch:
//   row_i = (M[i][0], M[i][1], M[i][2], c_i)
// ---------------------------------------------------------------------------
__global__ void flow_rot_kernel(const float* __restrict__ rot,
                                const float* __restrict__ trans,
                                float* __restrict__ Mws) {
    int b = threadIdx.x;
    if (b >= B) return;
    float rx = rot[b * 3 + 0], ry = rot[b * 3 + 1], rz = rot[b * 3 + 2];
    float cx = cosf(rx), sx = sinf(rx);
    float cy = cosf(ry), sy = sinf(ry);
    float cz = cosf(rz), sz = sinf(rz);
    // R = Rz @ Ry @ Rx ; M = R^T
    float m00 = cz * cy,                m01 = sz * cy,                m02 = -sy;
    float m10 = cz * sy * sx - sz * cx, m11 = sz * sy * sx + cz * cx, m12 = cy * sx;
    float m20 = cz * sy * cx + sz * sx, m21 = sz * sy * cx - cz * sx, m22 = cy * cx;
    float t0 = trans[0], t1 = trans[1], t2 = trans[2];
    float4* o = reinterpret_cast<float4*>(Mws) + b * 3;
    o[0] = make_float4(m00, m01, m02, m00 * t0 + m01 * t1 + m02 * t2);
    o[1] = make_float4(m10, m11, m12, m10 * t0 + m11 * t1 + m12 * t2);
    o[2] = make_float4(m20, m21, m22, m20 * t0 + m21 * t1 + m22 * t2);
}

// ---------------------------------------------------------------------------
// Kernel 2: main flow kernel — round-2 structure (best measured: 85.5 us).
// One thread = 2 consecutive pixels of one batch; single load -> compute ->
// single NT store per thread; one-shot waves retire while stores drain.
//   depth: float2 load (8 B/lane, coalesced; L2-resident across batches)
//   out:   float4 nontemporal store (16 B/lane; nt keeps 478 MB stream out
//          of L2 — plain store measured +5.9 us)
// b = blockIdx.y is wave-uniform -> scalar M loads.
// ---------------------------------------------------------------------------
__global__ __launch_bounds__(256) void flow_main_kernel(
        const float* __restrict__ depth,
        const float* __restrict__ Mws,
        float* __restrict__ out) {
    const int b  = blockIdx.y;
    const int t  = blockIdx.x * 256 + threadIdx.x;   // pixel-pair index
    const int n0 = t * 2;
    if (n0 >= HW) return;

    const float4* Mb = reinterpret_cast<const float4*>(Mws) + b * 3;
    const float4 r0 = Mb[0];
    const float4 r1 = Mb[1];
    const float4 r2 = Mb[2];

    const vfloat2 d2 = *reinterpret_cast<const vfloat2*>(depth + n0);

    int y0 = n0 / W;            // constant divisor -> magic-mul
    int x0 = n0 - y0 * W;
    int x1 = x0 + 1, y1 = y0;
    if (x1 == W) { x1 = 0; y1 += 1; }   // row wrap (HW even -> never crosses batch)

    float xs[2] = { (float)x0, (float)x1 };
    float ys[2] = { (float)y0, (float)y1 };
    float ds[2] = { d2.x, d2.y };
    float fo[4];

#pragma unroll
    for (int i = 0; i < 2; ++i) {
        float px = (xs[i] - CXc) * (1.0f / FXc);
        float py = (ys[i] - CYc) * (1.0f / FYc);
        // s = M @ (px, py, 1)
        float s0 = fmaf(r0.x, px, fmaf(r0.y, py, r0.z));
        float s1 = fmaf(r1.x, px, fmaf(r1.y, py, r1.z));
        float s2 = fmaf(r2.x, px, fmaf(r2.y, py, r2.z));
        // q = d * s - c   (== R^T (d*n - t))
        float d  = ds[i];
        float q0 = fmaf(d, s0, -r0.w);
        float q1 = fmaf(d, s1, -r1.w);
        float q2 = fmaf(d, s2, -r2.w);
        float inv = __builtin_amdgcn_rcpf(q2);   // 1-ulp approx, threshold 7.9e-3
        fo[2 * i + 0] = fmaf(q0 * inv, FXc, CXc - xs[i]) * (1.0f / (float)W);
        fo[2 * i + 1] = fmaf(q1 * inv, FYc, CYc - ys[i]) * (1.0f / (float)H);
    }

    vfloat4 o;
    o.x = fo[0]; o.y = fo[1]; o.z = fo[2]; o.w = fo[3];
    const size_t off = ((size_t)b * HW + n0) * 2;   // 16B-aligned (n0 even)
    __builtin_nontemporal_store(o, reinterpret_cast<vfloat4*>(out + off));
}

// ---------------------------------------------------------------------------
extern "C" void kernel_launch(void* const* d_in, const int* in_sizes, int n_in,
                              void* d_out, int out_size, void* d_ws, size_t ws_size,
                              hipStream_t stream) {
    const float* rotations   = (const float*)d_in[0];   // (B, 3)
    const float* depth       = (const float*)d_in[1];   // (H, W)
    const float* translation = (const float*)d_in[2];   // (3,)
    float*       out         = (float*)d_out;           // (B, H, W, 2)
    float*       Mws         = (float*)d_ws;            // B * 12 floats = 6 KB

    flow_rot_kernel<<<1, 128, 0, stream>>>(rotations, translation, Mws);

    dim3 grid((NPAIR + 255) / 256, B);                  // (912, 128)
    flow_main_kernel<<<grid, 256, 0, stream>>>(depth, Mws, out);
}